// Round 1
// baseline (97.576 us; speedup 1.0000x reference)
//
#include <hip/hip_runtime.h>
#include <math.h>

#define NB    64          // batches
#define NT    262144      // samples per batch
#define CH    64          // chunk length (samples per lane)
#define NCK   (NT/CH)     // 4096 chunks per batch
#define NBANDS 6

// ws layout (floats)
#define COEF_OFF 0                               // [NB][6][5]
#define MAT_OFF  4096                            // [NB][12][144]: 0..5 = A^(64*2^l), 6..11 = A^(4096*2^l)
#define T_OFF    (MAT_OFF + NB*1728)             // [NB][64][12] wave totals
#define WPRE_OFF (T_OFF + NB*64*12)              // [NB][64][12] state entering each wave
                                                 //   ALSO aliased as V-table [NB][64][12] between
                                                 //   k_prep and k_passA (k_scanW overwrites it later;
                                                 //   stream order k_prep->passA->scanW makes this safe)
#define D_OFF    (WPRE_OFF + NB*64*12)           // [NB][NCK][12] within-wave exclusive states

struct Coef { float b0, b1, b2, a1, a2; };

__device__ __forceinline__ float rfl(float x) {
  return __int_as_float(__builtin_amdgcn_readfirstlane(__float_as_int(x)));
}

__device__ __forceinline__ float cascade_step(float v, float s[12], const Coef cf[NBANDS]) {
#pragma unroll
  for (int k = 0; k < NBANDS; ++k) {
    float s1 = s[2*k], s2 = s[2*k+1];
    float y   = fmaf(cf[k].b0, v, s1);
    float ns1 = fmaf(cf[k].b1, v, fmaf(-cf[k].a1, y, s2));
    float ns2 = fmaf(cf[k].b2, v, -cf[k].a2 * y);
    s[2*k]   = ns1;
    s[2*k+1] = ns2;
    v = y;
  }
  return v;
}

// coefs are wave-uniform: pin them to SGPRs
__device__ __forceinline__ void load_coefs(const float* ws, int batch, Coef cf[NBANDS]) {
  const float* c = ws + COEF_OFF + batch*30;
#pragma unroll
  for (int k = 0; k < NBANDS; ++k) {
    cf[k].b0 = rfl(c[5*k+0]); cf[k].b1 = rfl(c[5*k+1]); cf[k].b2 = rfl(c[5*k+2]);
    cf[k].a1 = rfl(c[5*k+3]); cf[k].a2 = rfl(c[5*k+4]);
  }
}

// ---------------- kernel 1: coefficients + power matrices + V table (merged) ----------------
__global__ __launch_bounds__(64) void k_prep(const float* __restrict__ p, const float* __restrict__ W,
                                             const float* __restrict__ bias, const int* __restrict__ srp,
                                             float* __restrict__ ws) {
  __shared__ float prmS[18];
  __shared__ float cfS[30];
  __shared__ float M0[144], M1[144];
  int b = blockIdx.x, tid = threadIdx.x;
  const float lo[18] = {-24.f,20.f,0.1f,  -24.f,200.f,0.1f,  -24.f,200.f,0.1f,
                        -24.f,2000.f,0.1f, -24.f,4000.f,0.1f, -24.f,4000.f,0.1f};
  const float hi[18] = { 24.f,200.f,10.f,  24.f,2000.f,10.f,  24.f,2000.f,10.f,
                         24.f,8000.f,10.f, 24.f,12000.f,10.f, 24.f,12000.f,10.f};
  if (tid < 18) {
    float acc = bias[tid];
    for (int j = 0; j < 22; ++j) acc = fmaf(W[tid*22+j], p[b*22+j], acc);
    float sg = 1.f / (1.f + expf(-acc));
    prmS[tid] = sg * (hi[tid] - lo[tid]) + lo[tid];
  }
  __syncthreads();
  if (tid < 6) {
    int k = tid;
    float g = prmS[3*k], f = prmS[3*k+1], q = prmS[3*k+2];
    float sr = (float)srp[0];
    float A  = powf(10.f, g * (1.f/40.f));
    float w0 = 6.28318530717958647692f * (f / sr);
    float al = sinf(w0) / (2.f*q);
    float c  = cosf(w0);
    float sA = sqrtf(A);
    float b0,b1,b2,a0,a1,a2;
    if (k == 0) {            // low shelf
      b0 = A*((A+1.f) - (A-1.f)*c + 2.f*sA*al);
      b1 = 2.f*A*((A-1.f) - (A+1.f)*c);
      b2 = A*((A+1.f) - (A-1.f)*c - 2.f*sA*al);
      a0 = (A+1.f) + (A-1.f)*c + 2.f*sA*al;
      a1 = -2.f*((A-1.f) + (A+1.f)*c);
      a2 = (A+1.f) + (A-1.f)*c - 2.f*sA*al;
    } else if (k == 5) {     // high shelf
      b0 = A*((A+1.f) + (A-1.f)*c + 2.f*sA*al);
      b1 = -2.f*A*((A-1.f) + (A+1.f)*c);
      b2 = A*((A+1.f) + (A-1.f)*c - 2.f*sA*al);
      a0 = (A+1.f) - (A-1.f)*c + 2.f*sA*al;
      a1 = 2.f*((A-1.f) - (A+1.f)*c);
      a2 = (A+1.f) - (A-1.f)*c - 2.f*sA*al;
    } else {                 // peaking
      b0 = 1.f + al*A;
      b1 = -2.f*c;
      b2 = 1.f - al*A;
      a0 = 1.f + al/A;
      a1 = -2.f*c;
      a2 = 1.f - al/A;
    }
    float inv = 1.f/a0;
    float* cws = ws + COEF_OFF + b*30;
    cws[5*k+0] = cfS[5*k+0] = b0*inv;
    cws[5*k+1] = cfS[5*k+1] = b1*inv;
    cws[5*k+2] = cfS[5*k+2] = b2*inv;
    cws[5*k+3] = cfS[5*k+3] = a1*inv;
    cws[5*k+4] = cfS[5*k+4] = a2*inv;
  }
  __syncthreads();

  Coef cf[NBANDS];
#pragma unroll
  for (int k = 0; k < NBANDS; ++k) {
    cf[k].b0 = cfS[5*k+0]; cf[k].b1 = cfS[5*k+1]; cf[k].b2 = cfS[5*k+2];
    cf[k].a1 = cfS[5*k+3]; cf[k].a2 = cfS[5*k+4];
  }
  if (tid < 12) {
    float s[12];
#pragma unroll
    for (int r = 0; r < 12; ++r) s[r] = (r == tid) ? 1.f : 0.f;
    cascade_step(0.f, s, cf);
#pragma unroll
    for (int r = 0; r < 12; ++r) M0[r*12 + tid] = s[r];   // M0 = A (state transition)
  }
  __syncthreads();

  // per-thread V accumulator: w = A^(63-tid) * B, built from the squaring-loop intermediates.
  // B = state after one step with x=1 from zero state.
  float w[12];
#pragma unroll
  for (int r = 0; r < 12; ++r) w[r] = 0.f;
  cascade_step(1.f, w, cf);          // w = B
  int e63 = 63 - tid;

  float* S = M0; float* D = M1;
  float* mout = ws + MAT_OFF + (size_t)b*1728;
  for (int q = 0; q < 6; ++q) {       // S == A^(2^q) at loop entry; -> A^64 after
    if ((e63 >> q) & 1) {
      float t[12];
#pragma unroll
      for (int r = 0; r < 12; ++r) {
        float acc = 0.f;
#pragma unroll
        for (int k = 0; k < 12; ++k) acc = fmaf(S[r*12+k], w[k], acc);
        t[r] = acc;
      }
#pragma unroll
      for (int r = 0; r < 12; ++r) w[r] = t[r];
    }
    for (int e = tid; e < 144; e += 64) {
      int r = e/12, c = e%12;
      float acc = 0.f;
#pragma unroll
      for (int k = 0; k < 12; ++k) acc = fmaf(S[r*12+k], S[k*12+c], acc);
      D[e] = acc;
    }
    __syncthreads();
    float* t = S; S = D; D = t;
  }
  // store V[t] = A^(63-t)*B into the WPRE region (consumed by passA, overwritten by k_scanW)
  {
    float* vout = ws + WPRE_OFF + (size_t)b*768;
#pragma unroll
    for (int r = 0; r < 12; ++r) vout[tid*12 + r] = w[r];
  }
  for (int e = tid; e < 144; e += 64) mout[e] = S[e];
  for (int l = 1; l < 12; ++l) {      // l=1..5: A^(64*2^l); l=6..11: A^(4096*2^(l-6))
    for (int e = tid; e < 144; e += 64) {
      int r = e/12, c = e%12;
      float acc = 0.f;
#pragma unroll
      for (int k = 0; k < 12; ++k) acc = fmaf(S[r*12+k], S[k*12+c], acc);
      D[e] = acc;
    }
    __syncthreads();
    float* t = S; S = D; D = t;
    for (int e = tid; e < 144; e += 64) mout[l*144 + e] = S[e];
  }
}

// ---------------- passA: chunk finals via V-dot (no cascade, no LDS staging) + in-wave KS scan ----------------
// s_final(chunk, zero init) = sum_t V[t] * x[t]  -- dependency-free, 12 FMA/sample with
// wave-uniform (SGPR) multipliers. Sample order is irrelevant, so each lane reads its own
// chunk directly with lane-strided float4 loads (adjacent re-touches of each 64B line merge in MSHR/L1).
__global__ __launch_bounds__(256) void k_passA(const float* __restrict__ x,
                                               const float* __restrict__ Vt,
                                               float* __restrict__ ws) {
  __shared__ float KM[6][144];
  int tid = threadIdx.x, wib = tid >> 6, lane = tid & 63;
  int gw = blockIdx.x*4 + wib;
  int batch = gw >> 6, wv = gw & 63;
  int batch_b = blockIdx.x >> 4;        // batch is block-uniform (16 blocks per batch)

  const float* mb = ws + MAT_OFF + (size_t)batch_b*1728;
  for (int e = tid; e < 864; e += 256) KM[e/144][e%144] = mb[e];
  __syncthreads();

  const float4* xp = (const float4*)x + (size_t)batch*65536 + (size_t)wv*1024 + (size_t)lane*16;
  const float* Vb = Vt + (size_t)batch_b*768;   // wave-uniform base -> scalar loads

  // prefetch the whole chunk (16 independent loads in flight)
  float4 xv[16];
#pragma unroll
  for (int k = 0; k < 16; ++k) xv[k] = xp[k];

  float s[12];
#pragma unroll
  for (int r = 0; r < 12; ++r) s[r] = 0.f;

#pragma unroll
  for (int k = 0; k < 16; ++k) {
    const float* vr = Vb + k*48;        // V rows for samples 4k..4k+3
#pragma unroll
    for (int r = 0; r < 12; ++r) {
      float acc = s[r];
      acc = fmaf(vr[r],      xv[k].x, acc);
      acc = fmaf(vr[12 + r], xv[k].y, acc);
      acc = fmaf(vr[24 + r], xv[k].z, acc);
      acc = fmaf(vr[36 + r], xv[k].w, acc);
      s[r] = acc;
    }
  }

  // in-wave inclusive Kogge-Stone over chunk finals
#pragma unroll
  for (int l = 0; l < 6; ++l) {
    const int pd = 1 << l;
    float nb[12];
#pragma unroll
    for (int r = 0; r < 12; ++r) nb[r] = __shfl_up(s[r], pd);
    if (lane >= pd) {
#pragma unroll
      for (int r = 0; r < 12; ++r) {
        float acc = s[r];
#pragma unroll
        for (int c = 0; c < 12; ++c) acc = fmaf(KM[l][r*12+c], nb[c], acc);
        s[r] = acc;
      }
    }
  }

  if (lane == 63) {
    float4* tp = (float4*)(ws + T_OFF + ((size_t)batch*64 + wv)*12);
    tp[0] = make_float4(s[0], s[1], s[2],  s[3]);
    tp[1] = make_float4(s[4], s[5], s[6],  s[7]);
    tp[2] = make_float4(s[8], s[9], s[10], s[11]);
  }

  float e[12];
#pragma unroll
  for (int r = 0; r < 12; ++r) e[r] = __shfl_up(s[r], 1);
  if (lane == 0) {
#pragma unroll
    for (int r = 0; r < 12; ++r) e[r] = 0.f;
  }
  int chunk = wv*64 + lane;
  float4* dp = (float4*)(ws + D_OFF + ((size_t)batch*NCK + chunk)*12);
  dp[0] = make_float4(e[0], e[1], e[2],  e[3]);
  dp[1] = make_float4(e[4], e[5], e[6],  e[7]);
  dp[2] = make_float4(e[8], e[9], e[10], e[11]);
}

// ---------------- scan over wave totals ----------------
__global__ __launch_bounds__(64) void k_scanW(float* __restrict__ ws) {
  __shared__ float WM[6][144];
  int b = blockIdx.x, lane = threadIdx.x;
  const float* mb = ws + MAT_OFF + (size_t)b*1728 + 864;
  for (int e = lane; e < 864; e += 64) WM[e/144][e%144] = mb[e];
  __syncthreads();

  const float4* tp = (const float4*)(ws + T_OFF + ((size_t)b*64 + lane)*12);
  float4 a0 = tp[0], a1 = tp[1], a2 = tp[2];
  float s[12] = {a0.x,a0.y,a0.z,a0.w, a1.x,a1.y,a1.z,a1.w, a2.x,a2.y,a2.z,a2.w};

#pragma unroll
  for (int l = 0; l < 6; ++l) {
    const int pd = 1 << l;
    float nb[12];
#pragma unroll
    for (int r = 0; r < 12; ++r) nb[r] = __shfl_up(s[r], pd);
    if (lane >= pd) {
#pragma unroll
      for (int r = 0; r < 12; ++r) {
        float acc = s[r];
#pragma unroll
        for (int c = 0; c < 12; ++c) acc = fmaf(WM[l][r*12+c], nb[c], acc);
        s[r] = acc;
      }
    }
  }
  float e[12];
#pragma unroll
  for (int r = 0; r < 12; ++r) e[r] = __shfl_up(s[r], 1);
  if (lane == 0) {
#pragma unroll
    for (int r = 0; r < 12; ++r) e[r] = 0.f;
  }
  float4* wp = (float4*)(ws + WPRE_OFF + ((size_t)b*64 + lane)*12);
  wp[0] = make_float4(e[0], e[1], e[2],  e[3]);
  wp[1] = make_float4(e[4], e[5], e[6],  e[7]);
  wp[2] = make_float4(e[8], e[9], e[10], e[11]);
}

// ---------------- passB: reconstruct incoming state + replay + write y ----------------
__global__ __launch_bounds__(256) void k_passB(const float* __restrict__ x, const float* __restrict__ ws,
                                               float* __restrict__ out) {
  __shared__ float4 buf[4][2][256];
  __shared__ float KM[6][144];
  int tid = threadIdx.x, wib = tid >> 6, lane = tid & 63;
  int gw = blockIdx.x*4 + wib;
  int batch = gw >> 6, wv = gw & 63;
  int batch_b = blockIdx.x >> 4;

  const float* mb = ws + MAT_OFF + (size_t)batch_b*1728;
  for (int e = tid; e < 864; e += 256) KM[e/144][e%144] = mb[e];
  __syncthreads();

  const float4* x4 = (const float4*)x;
  float4* out4 = (float4*)out;
  size_t gbase4 = (size_t)batch*65536 + (size_t)wv*1024;
  int r2 = lane >> 2, c2 = lane & 3;
  float4* bufA = buf[wib][0];
  float4* bufB = buf[wib][1];

  float4 va[4], vb[4];
#pragma unroll
  for (int j = 0; j < 4; ++j) va[j] = x4[gbase4 + (size_t)(j*16 + r2)*16 + c2];

  Coef cf[NBANDS];
  load_coefs(ws, batch, cf);

  // incoming state: E (within-wave exclusive) + A^(64*lane) * Wpre  (hides q0 load latency)
  int chunk = wv*64 + lane;
  const float4* dp = (const float4*)(ws + D_OFF + ((size_t)batch*NCK + chunk)*12);
  float4 e0 = dp[0], e1 = dp[1], e2 = dp[2];
  const float4* wp = (const float4*)(ws + WPRE_OFF + ((size_t)batch*64 + wv)*12);
  float4 w0 = wp[0], w1 = wp[1], w2 = wp[2];
  float R[12] = {w0.x,w0.y,w0.z,w0.w, w1.x,w1.y,w1.z,w1.w, w2.x,w2.y,w2.z,w2.w};
#pragma unroll
  for (int l = 0; l < 6; ++l) {
    float t[12];
#pragma unroll
    for (int r = 0; r < 12; ++r) {
      float acc = 0.f;
#pragma unroll
      for (int c = 0; c < 12; ++c) acc = fmaf(KM[l][r*12+c], R[c], acc);
      t[r] = acc;
    }
    bool sel = (lane >> l) & 1;
#pragma unroll
    for (int r = 0; r < 12; ++r) R[r] = sel ? t[r] : R[r];
  }
  float s[12] = {e0.x+R[0], e0.y+R[1], e0.z+R[2],  e0.w+R[3],
                 e1.x+R[4], e1.y+R[5], e1.z+R[6],  e1.w+R[7],
                 e2.x+R[8], e2.y+R[9], e2.z+R[10], e2.w+R[11]};

#pragma unroll
  for (int j = 0; j < 4; ++j) bufA[c2*64 + j*16 + r2] = va[j];
  asm volatile("s_waitcnt lgkmcnt(0)" ::: "memory");

#pragma unroll
  for (int q = 0; q < 4; ++q) {
    float4* bp = (q & 1) ? bufB : bufA;
    float4* bn = (q & 1) ? bufA : bufB;
    float4* vr = (q & 1) ? va : vb;
    if (q < 3) {
#pragma unroll
      for (int j = 0; j < 4; ++j)
        vr[j] = x4[gbase4 + (size_t)(j*16 + r2)*16 + (q+1)*4 + c2];
    }
#pragma unroll
    for (int t = 0; t < 4; ++t) {
      float4 xv = bp[t*64 + lane];
      float4 yv;
      yv.x = cascade_step(xv.x, s, cf);
      yv.y = cascade_step(xv.y, s, cf);
      yv.z = cascade_step(xv.z, s, cf);
      yv.w = cascade_step(xv.w, s, cf);
      bp[t*64 + lane] = yv;
    }
    asm volatile("s_waitcnt lgkmcnt(0)" ::: "memory");
    // transpose coop-store of quarter q (16 full 64B lines per instr)
#pragma unroll
    for (int j = 0; j < 4; ++j) {
      float4 w = bp[c2*64 + j*16 + r2];
      out4[gbase4 + (size_t)(j*16 + r2)*16 + q*4 + c2] = w;
    }
    if (q < 3) {
#pragma unroll
      for (int j = 0; j < 4; ++j) bn[c2*64 + j*16 + r2] = vr[j];
      asm volatile("s_waitcnt lgkmcnt(0)" ::: "memory");
    }
  }
}

extern "C" void kernel_launch(void* const* d_in, const int* in_sizes, int n_in,
                              void* d_out, int out_size, void* d_ws, size_t ws_size,
                              hipStream_t stream) {
  const float* x    = (const float*)d_in[0];
  const float* p    = (const float*)d_in[1];
  const float* W    = (const float*)d_in[2];
  const float* bias = (const float*)d_in[3];
  const int*   sr   = (const int*)d_in[4];
  float* ws  = (float*)d_ws;
  float* out = (float*)d_out;

  int passBlocks = (NB * NCK) / 256;   // 1024 blocks x 4 waves
  hipLaunchKernelGGL(k_prep,  dim3(NB),         dim3(64),  0, stream, p, W, bias, sr, ws);
  hipLaunchKernelGGL(k_passA, dim3(passBlocks), dim3(256), 0, stream, x, ws + WPRE_OFF, ws);
  hipLaunchKernelGGL(k_scanW, dim3(NB),         dim3(64),  0, stream, ws);
  hipLaunchKernelGGL(k_passB, dim3(passBlocks), dim3(256), 0, stream, x, ws, out);
}